// Round 4
// baseline (145.721 us; speedup 1.0000x reference)
//
#include <hip/hip_runtime.h>
#include <hip/hip_cooperative_groups.h>
#include <math.h>

namespace cg = cooperative_groups;

// Problem constants (from reference)
#define P_TOTAL 10000
#define G_TOTAL 6400
#define C_CLS   18
#define REC_DW  40        // gaussian record stride in dwords (160 B)
#define CS_SH   3         // cell = 8 voxels = 4 m
#define NCX     25
#define NCY     25
#define NCELL   (NCX * NCY)
#define MAXE    256       // entry slots per cell (mean fill ~50)
#define TPP     16        // threads per point in gather
#define NBLK    625       // 625 blocks * 16 points = 10000 points
#define NTHR    256

// ---------------- device helpers (shared by fused + fallback) ----------------

__device__ __forceinline__ void prep_one(int g,
                                         const float* __restrict__ means3D,
                                         const float* __restrict__ opacities,
                                         const float* __restrict__ semantics,
                                         const float* __restrict__ scales,
                                         const float* __restrict__ cov3D,
                                         float* __restrict__ rec,
                                         int* __restrict__ counts,
                                         int4* __restrict__ entries) {
    float mx = means3D[g * 3 + 0];
    float my = means3D[g * 3 + 1];
    float mz = means3D[g * 3 + 2];
    float sx = scales[g * 3 + 0];
    float sy = scales[g * 3 + 1];
    float sz = scales[g * 3 + 2];
    // (mu - PC_MIN)/0.5 == (mu - PC_MIN)*2 exactly
    int mix = (int)((mx + 50.0f) * 2.0f);
    int miy = (int)((my + 50.0f) * 2.0f);
    int miz = (int)((mz + 5.0f) * 2.0f);
    // radii = ceil(max(s)*3.0/0.5): *3.0 rounds, *2 exact
    int r = (int)ceilf((fmaxf(fmaxf(sx, sy), sz) * 3.0f) * 2.0f);
    int w = 2 * r;

    float* o = rec + (size_t)g * REC_DW;
    o[4] = mx; o[5] = my; o[6] = mz; o[7] = opacities[g];
    const float* cv = cov3D + (size_t)g * 9;
    o[8]  = cv[0];  // xx
    o[9]  = cv[4];  // yy
    o[10] = cv[8];  // zz
    o[11] = cv[1];  // xy
    o[12] = cv[5];  // yz
    o[13] = cv[2];  // xz
    const float* s = semantics + (size_t)g * C_CLS;
#pragma unroll
    for (int c = 0; c < C_CLS; ++c) o[16 + c] = s[c];

    // scatter packed box entry into every overlapped cell
    int minx = mix - r, miny = miy - r, minz = miz - r;
    int cx0 = max(minx, 0) >> CS_SH;
    int cx1 = min(minx + w, 199) >> CS_SH;
    int cy0 = max(miny, 0) >> CS_SH;
    int cy1 = min(miny + w, 199) >> CS_SH;
    int4 e = make_int4(minx, miny, minz, (w << 16) | g);
    for (int cy = cy0; cy <= cy1; ++cy) {
        for (int cx = cx0; cx <= cx1; ++cx) {
            int cell = cy * NCX + cx;
            int slot = atomicAdd(&counts[cell], 1);
            if (slot < MAXE) entries[(size_t)cell * MAXE + slot] = e;
        }
    }
}

__device__ __forceinline__ void gather_one(int pt, int lane,
                                           const float* __restrict__ pts,
                                           const float* __restrict__ rec,
                                           const int* __restrict__ counts,
                                           const int4* __restrict__ entries,
                                           float* __restrict__ out) {
    float px = pts[pt * 3 + 0];
    float py = pts[pt * 3 + 1];
    float pz = pts[pt * 3 + 2];
    int pix = (int)((px + 50.0f) * 2.0f);
    int piy = (int)((py + 50.0f) * 2.0f);
    int piz = (int)((pz + 5.0f) * 2.0f);

    int cell = (piy >> CS_SH) * NCX + (pix >> CS_SH);
    int cnt = min(counts[cell], MAXE);
    const int4* eb = entries + (size_t)cell * MAXE;

    float acc[C_CLS];
#pragma unroll
    for (int c = 0; c < C_CLS; ++c) acc[c] = 0.0f;

#pragma unroll 2
    for (int i = lane; i < cnt; i += TPP) {
        int4 b = eb[i];                          // coalesced 16B within cell
        unsigned w = ((unsigned)b.w) >> 16;
        unsigned ux = (unsigned)(pix - b.x);
        unsigned uy = (unsigned)(piy - b.y);
        unsigned uz = (unsigned)(piz - b.z);
        if (ux <= w && uy <= w && uz <= w) {
            int gid = b.w & 0xffff;
            const float* o = rec + (size_t)gid * REC_DW;
            float4 g0 = *(const float4*)(o + 4);   // mu, op
            float4 g1 = *(const float4*)(o + 8);   // cxx cyy czz cxy
            float2 g2 = *(const float2*)(o + 12);  // cyz cxz
            float dx = px - g0.x, dy = py - g0.y, dz = pz - g0.z;
            float pw = -0.5f * (g1.x * dx * dx + g1.y * dy * dy + g1.z * dz * dz)
                       - g1.w * dx * dy - g2.x * dy * dz - g2.y * dx * dz;
            float wgt = __expf(pw) * g0.w;
            float4 s0 = *(const float4*)(o + 16);
            float4 s1 = *(const float4*)(o + 20);
            float4 s2 = *(const float4*)(o + 24);
            float4 s3 = *(const float4*)(o + 28);
            float2 s4 = *(const float2*)(o + 32);
            acc[0]  = fmaf(wgt, s0.x, acc[0]);  acc[1]  = fmaf(wgt, s0.y, acc[1]);
            acc[2]  = fmaf(wgt, s0.z, acc[2]);  acc[3]  = fmaf(wgt, s0.w, acc[3]);
            acc[4]  = fmaf(wgt, s1.x, acc[4]);  acc[5]  = fmaf(wgt, s1.y, acc[5]);
            acc[6]  = fmaf(wgt, s1.z, acc[6]);  acc[7]  = fmaf(wgt, s1.w, acc[7]);
            acc[8]  = fmaf(wgt, s2.x, acc[8]);  acc[9]  = fmaf(wgt, s2.y, acc[9]);
            acc[10] = fmaf(wgt, s2.z, acc[10]); acc[11] = fmaf(wgt, s2.w, acc[11]);
            acc[12] = fmaf(wgt, s3.x, acc[12]); acc[13] = fmaf(wgt, s3.y, acc[13]);
            acc[14] = fmaf(wgt, s3.z, acc[14]); acc[15] = fmaf(wgt, s3.w, acc[15]);
            acc[16] = fmaf(wgt, s4.x, acc[16]); acc[17] = fmaf(wgt, s4.y, acc[17]);
        }
    }

    // reduce across the 16 lanes of this point-group
#pragma unroll
    for (int m = 8; m >= 1; m >>= 1) {
#pragma unroll
        for (int c = 0; c < C_CLS; ++c)
            acc[c] += __shfl_xor(acc[c], m, 64);
    }

    if (lane == 0) {
        float* dst = out + (size_t)pt * C_CLS;
#pragma unroll
        for (int c = 0; c < C_CLS; ++c) dst[c] = acc[c];
    }
}

// ---------------- fused cooperative kernel ----------------

__global__ void __launch_bounds__(NTHR)
la_fused(const float* __restrict__ pts,
         const float* __restrict__ means3D,
         const float* __restrict__ opacities,
         const float* __restrict__ semantics,
         const float* __restrict__ scales,
         const float* __restrict__ cov3D,
         float* __restrict__ rec,
         int* __restrict__ counts,
         int4* __restrict__ entries,
         float* __restrict__ out) {
    cg::grid_group grid = cg::this_grid();
    const int tid = blockIdx.x * NTHR + threadIdx.x;

    // phase 1: zero cell counts
    if (tid < NCELL) counts[tid] = 0;
    grid.sync();

    // phase 2: build gaussian records + scatter box entries into cells
    if (tid < G_TOTAL)
        prep_one(tid, means3D, opacities, semantics, scales, cov3D, rec, counts, entries);
    grid.sync();

    // phase 3: per-point gather (16 lanes per point)
    const int pt = blockIdx.x * 16 + (threadIdx.x >> 4);
    if (pt < P_TOTAL)
        gather_one(pt, threadIdx.x & 15, pts, rec, counts, entries, out);
}

// ---------------- fallback (3 separate kernels) ----------------

__global__ void la_zero(int* __restrict__ counts) {
    int i = threadIdx.x + blockIdx.x * blockDim.x;
    if (i < NCELL) counts[i] = 0;
}

__global__ void la_prep(const float* __restrict__ means3D,
                        const float* __restrict__ opacities,
                        const float* __restrict__ semantics,
                        const float* __restrict__ scales,
                        const float* __restrict__ cov3D,
                        float* __restrict__ rec,
                        int* __restrict__ counts,
                        int4* __restrict__ entries) {
    int g = blockIdx.x * blockDim.x + threadIdx.x;
    if (g < G_TOTAL)
        prep_one(g, means3D, opacities, semantics, scales, cov3D, rec, counts, entries);
}

__global__ void la_gather(const float* __restrict__ pts,
                          const float* __restrict__ rec,
                          const int* __restrict__ counts,
                          const int4* __restrict__ entries,
                          float* __restrict__ out) {
    const int pt = blockIdx.x * 16 + (threadIdx.x >> 4);
    if (pt < P_TOTAL)
        gather_one(pt, threadIdx.x & 15, pts, rec, counts, entries, out);
}

extern "C" void kernel_launch(void* const* d_in, const int* in_sizes, int n_in,
                              void* d_out, int out_size, void* d_ws, size_t ws_size,
                              hipStream_t stream) {
    const float* pts      = (const float*)d_in[0];
    const float* means3D  = (const float*)d_in[1];
    const float* opac     = (const float*)d_in[2];
    const float* sem      = (const float*)d_in[3];
    const float* scales   = (const float*)d_in[4];
    const float* cov3D    = (const float*)d_in[5];
    float* out = (float*)d_out;

    char* ws = (char*)d_ws;
    float* rec      = (float*)ws;                              // 1,024,000 B
    int*   counts   = (int*)(ws + 1024000);                    // 2,500 B
    int4*  entries  = (int4*)(ws + 1024000 + 4096);            // 2,560,000 B

    void* args[] = {(void*)&pts, (void*)&means3D, (void*)&opac, (void*)&sem,
                    (void*)&scales, (void*)&cov3D, (void*)&rec, (void*)&counts,
                    (void*)&entries, (void*)&out};
    hipError_t err = hipLaunchCooperativeKernel((const void*)la_fused,
                                                dim3(NBLK), dim3(NTHR),
                                                args, 0, stream);
    if (err != hipSuccess) {
        // fallback: 3 dependent launches (round-3 behavior)
        la_zero<<<(NCELL + 255) / 256, 256, 0, stream>>>(counts);
        la_prep<<<(G_TOTAL + 255) / 256, 256, 0, stream>>>(means3D, opac, sem, scales,
                                                           cov3D, rec, counts, entries);
        la_gather<<<(P_TOTAL + 15) / 16, 256, 0, stream>>>(pts, rec, counts, entries, out);
    }
}

// Round 5
// 46.979 us; speedup vs baseline: 3.1019x; 3.1019x over previous
//
#include <hip/hip_runtime.h>
#include <math.h>

// Problem constants (from reference)
#define P_TOTAL 10000
#define G_TOTAL 6400
#define C_CLS   18
#define CS_SH   3                   // cell = 8 voxels = 4 m
#define NCX     25
#define NCELL   (NCX * NCX)
#define NPTS    16                  // points per block
#define CAP     192                 // entries per cell list (mean fill ~50, max ~85)
#define NTHR    256
#define NBLK    (P_TOTAL / NPTS)    // 625
#define GPT     (G_TOTAL / NTHR)    // 25 gaussians per thread

// Single kernel: per-block private binning in LDS -> gather. No cross-block deps.
__global__ void __launch_bounds__(NTHR)
la_one(const float* __restrict__ pts,
       const float* __restrict__ means3D,
       const float* __restrict__ opacities,
       const float* __restrict__ semantics,
       const float* __restrict__ scales,
       const float* __restrict__ cov3D,
       float* __restrict__ out) {
    __shared__ int  smap[NCELL];        // cell -> slot (or -1 / -2 pending)
    __shared__ int  scnt[NPTS];
    __shared__ int  spslot[NPTS];       // point -> slot
    __shared__ int  snuniq;
    __shared__ int4 slist[NPTS][CAP];   // 48 KB

    const int t = threadIdx.x;

    // init
    for (int i = t; i < NCELL; i += NTHR) smap[i] = -1;
    if (t < NPTS) scnt[t] = 0;
    if (t == 0) snuniq = 0;
    __syncthreads();

    // phase A: claim the block's (<=16 unique) cells
    if (t < NPTS) {
        int pt = blockIdx.x * NPTS + t;
        float px = pts[pt * 3 + 0];
        float py = pts[pt * 3 + 1];
        int pix = (int)((px + 50.0f) * 2.0f);
        int piy = (int)((py + 50.0f) * 2.0f);
        int cell = (piy >> CS_SH) * NCX + (pix >> CS_SH);
        int old = atomicCAS(&smap[cell], -1, -2);
        if (old == -1) {
            int s = atomicAdd(&snuniq, 1);
            smap[cell] = s;
        }
        spslot[t] = cell;   // stash cell; resolve to slot after barrier
    }
    __syncthreads();
    if (t < NPTS) spslot[t] = smap[spslot[t]];
    __syncthreads();

    // phase B: sweep all gaussians, append box entries to needed cell lists
    for (int k = 0; k < GPT; ++k) {
        int g = t + k * NTHR;           // coalesced across the wave
        float mx = means3D[g * 3 + 0];
        float my = means3D[g * 3 + 1];
        float mz = means3D[g * 3 + 2];
        float sx = scales[g * 3 + 0];
        float sy = scales[g * 3 + 1];
        float sz = scales[g * 3 + 2];
        // (mu - PC_MIN)/0.5 == (mu - PC_MIN)*2 exactly
        int mix = (int)((mx + 50.0f) * 2.0f);
        int miy = (int)((my + 50.0f) * 2.0f);
        int miz = (int)((mz + 5.0f) * 2.0f);
        // radii = ceil(max(s)*3.0/0.5): *3.0 rounds, *2 exact
        int r = (int)ceilf((fmaxf(fmaxf(sx, sy), sz) * 3.0f) * 2.0f);
        int w = 2 * r;
        int minx = mix - r, miny = miy - r, minz = miz - r;
        int cx0 = max(minx, 0) >> CS_SH;
        int cx1 = min(minx + w, 199) >> CS_SH;
        int cy0 = max(miny, 0) >> CS_SH;
        int cy1 = min(miny + w, 199) >> CS_SH;
        int4 e = make_int4(minx, miny, minz, (w << 16) | g);
        for (int cy = cy0; cy <= cy1; ++cy) {
            for (int cx = cx0; cx <= cx1; ++cx) {
                int s = smap[cy * NCX + cx];
                if (s >= 0) {
                    int pos = atomicAdd(&scnt[s], 1);
                    if (pos < CAP) slist[s][pos] = e;
                }
            }
        }
    }
    __syncthreads();

    // phase C: per-point gather, 16 lanes per point
    const int grp = t >> 4, lane = t & 15;
    const int pt = blockIdx.x * NPTS + grp;
    float px = pts[pt * 3 + 0];
    float py = pts[pt * 3 + 1];
    float pz = pts[pt * 3 + 2];
    int pix = (int)((px + 50.0f) * 2.0f);
    int piy = (int)((py + 50.0f) * 2.0f);
    int piz = (int)((pz + 5.0f) * 2.0f);
    int s = spslot[grp];
    int n = min(scnt[s], CAP);

    float acc[C_CLS];
#pragma unroll
    for (int c = 0; c < C_CLS; ++c) acc[c] = 0.0f;

    for (int i = lane; i < n; i += NPTS) {
        int4 b = slist[s][i];
        unsigned w = ((unsigned)b.w) >> 16;
        unsigned ux = (unsigned)(pix - b.x);
        unsigned uy = (unsigned)(piy - b.y);
        unsigned uz = (unsigned)(piz - b.z);
        if (ux <= w && uy <= w && uz <= w) {
            int gid = b.w & 0xffff;
            float mx = means3D[gid * 3 + 0];
            float my = means3D[gid * 3 + 1];
            float mz = means3D[gid * 3 + 2];
            float op = opacities[gid];
            const float* cv = cov3D + (size_t)gid * 9;
            float dx = px - mx, dy = py - my, dz = pz - mz;
            float pw = -0.5f * (cv[0] * dx * dx + cv[4] * dy * dy + cv[8] * dz * dz)
                       - cv[1] * dx * dy - cv[5] * dy * dz - cv[2] * dx * dz;
            float wgt = __expf(pw) * op;
            const float* sm = semantics + (size_t)gid * C_CLS;
#pragma unroll
            for (int c = 0; c < C_CLS; ++c) acc[c] = fmaf(wgt, sm[c], acc[c]);
        }
    }

    // reduce across the 16 lanes of this point-group
#pragma unroll
    for (int m = 8; m >= 1; m >>= 1) {
#pragma unroll
        for (int c = 0; c < C_CLS; ++c)
            acc[c] += __shfl_xor(acc[c], m, 64);
    }

    if (lane == 0) {
        float* dst = out + (size_t)pt * C_CLS;
#pragma unroll
        for (int c = 0; c < C_CLS; ++c) dst[c] = acc[c];
    }
}

extern "C" void kernel_launch(void* const* d_in, const int* in_sizes, int n_in,
                              void* d_out, int out_size, void* d_ws, size_t ws_size,
                              hipStream_t stream) {
    const float* pts      = (const float*)d_in[0];
    const float* means3D  = (const float*)d_in[1];
    const float* opac     = (const float*)d_in[2];
    const float* sem      = (const float*)d_in[3];
    const float* scales   = (const float*)d_in[4];
    const float* cov3D    = (const float*)d_in[5];
    float* out = (float*)d_out;

    la_one<<<NBLK, NTHR, 0, stream>>>(pts, means3D, opac, sem, scales, cov3D, out);
}

// Round 6
// 38.339 us; speedup vs baseline: 3.8008x; 1.2253x over previous
//
#include <hip/hip_runtime.h>
#include <math.h>

// Problem constants (from reference)
#define P_TOTAL 10000
#define G_TOTAL 6400
#define C_CLS   18
#define CS_SH   3                   // cell = 8 voxels = 4 m
#define NCX     25
#define NCELL   (NCX * NCX)         // 625
#define BCAP    256                 // box entries per cell (mean ~51, max ~100)
#define PCAP    160                 // points per cell (mean 16, Poisson tail << 160)
#define NTHR    256

// ---------------- K1: pack boxes + point cells (no atomics, no zero dep) ----------------

__global__ void la_pack(const float* __restrict__ pts,
                        const float* __restrict__ means3D,
                        const float* __restrict__ scales,
                        int4* __restrict__ boxes,
                        int* __restrict__ pcell) {
    int tid = blockIdx.x * NTHR + threadIdx.x;
    if (tid < G_TOTAL) {
        int g = tid;
        float mx = means3D[g * 3 + 0];
        float my = means3D[g * 3 + 1];
        float sx = scales[g * 3 + 0];
        float sy = scales[g * 3 + 1];
        float sz = scales[g * 3 + 2];
        // (mu - PC_MIN)/0.5 == (mu - PC_MIN)*2 exactly
        int mix = (int)((mx + 50.0f) * 2.0f);
        int miy = (int)((my + 50.0f) * 2.0f);
        float mz = means3D[g * 3 + 2];
        int miz = (int)((mz + 5.0f) * 2.0f);
        // radii = ceil(max(s)*3.0/0.5): *3.0 rounds, *2 exact
        int r = (int)ceilf((fmaxf(fmaxf(sx, sy), sz) * 3.0f) * 2.0f);
        int w = 2 * r;
        boxes[g] = make_int4(mix - r, miy - r, miz - r, (w << 16) | g);
    } else if (tid < G_TOTAL + P_TOTAL) {
        int p = tid - G_TOTAL;
        float px = pts[p * 3 + 0];
        float py = pts[p * 3 + 1];
        int pix = (int)((px + 50.0f) * 2.0f);
        int piy = (int)((py + 50.0f) * 2.0f);
        pcell[p] = (piy >> CS_SH) * NCX + (pix >> CS_SH);
    }
}

// ---------------- K2: one block per cell -> filter + gather ----------------

__global__ void __launch_bounds__(NTHR)
la_cell(const float* __restrict__ pts,
        const float* __restrict__ means3D,
        const float* __restrict__ opacities,
        const float* __restrict__ semantics,
        const float* __restrict__ cov3D,
        const int4* __restrict__ boxes,
        const int* __restrict__ pcell,
        float* __restrict__ out) {
    __shared__ int4 sbox[BCAP];
    __shared__ int  splist[PCAP];
    __shared__ int  snb, snp;

    const int t = threadIdx.x;
    const int cell = blockIdx.x;
    const int ccx = cell % NCX;
    const int ccy = cell / NCX;

    if (t == 0) { snb = 0; snp = 0; }
    __syncthreads();

    // phase 1: collect my cell's points (coalesced dword sweep)
    for (int i = t; i < P_TOTAL; i += NTHR) {
        if (pcell[i] == cell) {
            int s = atomicAdd(&snp, 1);
            if (s < PCAP) splist[s] = i;
        }
    }

    // phase 2: collect boxes overlapping my cell (coalesced int4 sweep, branchless test)
    for (int i = t; i < G_TOTAL; i += NTHR) {
        int4 b = boxes[i];                    // w<<16|g  (positive: w<=12, g<6400)
        int w = b.w >> 16;
        int cx0 = max(b.x, 0) >> CS_SH;
        int cx1 = min(b.x + w, 199) >> CS_SH;
        int cy0 = max(b.y, 0) >> CS_SH;
        int cy1 = min(b.y + w, 199) >> CS_SH;
        if (ccx >= cx0 && ccx <= cx1 && ccy >= cy0 && ccy <= cy1) {
            int s = atomicAdd(&snb, 1);
            if (s < BCAP) sbox[s] = b;
        }
    }
    __syncthreads();

    const int np = min(snp, PCAP);
    const int nb = min(snb, BCAP);
    const int grp = t >> 4, lane = t & 15;

    // phase 3: gather — 16 lanes per point, 16 points concurrently
    for (int base = 0; base < np; base += 16) {
        int idx = base + grp;
        int pt = -1;
        float px = 0.f, py = 0.f, pz = 0.f;
        int pix = 0x7f000000, piy = 0x7f000000, piz = 0x7f000000;  // fails all boxes
        if (idx < np) {
            pt = splist[idx];
            px = pts[pt * 3 + 0];
            py = pts[pt * 3 + 1];
            pz = pts[pt * 3 + 2];
            pix = (int)((px + 50.0f) * 2.0f);
            piy = (int)((py + 50.0f) * 2.0f);
            piz = (int)((pz + 5.0f) * 2.0f);
        }

        float acc[C_CLS];
#pragma unroll
        for (int c = 0; c < C_CLS; ++c) acc[c] = 0.0f;

        for (int i = lane; i < nb; i += 16) {
            int4 b = sbox[i];
            unsigned w  = ((unsigned)b.w) >> 16;
            unsigned ux = (unsigned)(pix - b.x);
            unsigned uy = (unsigned)(piy - b.y);
            unsigned uz = (unsigned)(piz - b.z);
            if (ux <= w && uy <= w && uz <= w) {
                int gid = b.w & 0xffff;
                float mx = means3D[gid * 3 + 0];
                float my = means3D[gid * 3 + 1];
                float mz = means3D[gid * 3 + 2];
                float op = opacities[gid];
                const float* cv = cov3D + (size_t)gid * 9;
                float dx = px - mx, dy = py - my, dz = pz - mz;
                float pw = -0.5f * (cv[0] * dx * dx + cv[4] * dy * dy + cv[8] * dz * dz)
                           - cv[1] * dx * dy - cv[5] * dy * dz - cv[2] * dx * dz;
                float wgt = __expf(pw) * op;
                const float* sm = semantics + (size_t)gid * C_CLS;
#pragma unroll
                for (int c = 0; c < C_CLS; ++c) acc[c] = fmaf(wgt, sm[c], acc[c]);
            }
        }

        // reduce across the 16 lanes of this point-group (stays within 16-lane blocks)
#pragma unroll
        for (int m = 8; m >= 1; m >>= 1) {
#pragma unroll
            for (int c = 0; c < C_CLS; ++c)
                acc[c] += __shfl_xor(acc[c], m, 64);
        }

        if (lane == 0 && pt >= 0) {
            float* dst = out + (size_t)pt * C_CLS;
#pragma unroll
            for (int c = 0; c < C_CLS; ++c) dst[c] = acc[c];
        }
    }
}

extern "C" void kernel_launch(void* const* d_in, const int* in_sizes, int n_in,
                              void* d_out, int out_size, void* d_ws, size_t ws_size,
                              hipStream_t stream) {
    const float* pts      = (const float*)d_in[0];
    const float* means3D  = (const float*)d_in[1];
    const float* opac     = (const float*)d_in[2];
    const float* sem      = (const float*)d_in[3];
    const float* scales   = (const float*)d_in[4];
    const float* cov3D    = (const float*)d_in[5];
    float* out = (float*)d_out;

    char* ws = (char*)d_ws;
    int4* boxes = (int4*)ws;                         // 102,400 B (written fully by K1)
    int*  pcell = (int*)(ws + 102400);               //  40,000 B (written fully by K1)

    const int k1_blocks = (G_TOTAL + P_TOTAL + NTHR - 1) / NTHR;  // 65
    la_pack<<<k1_blocks, NTHR, 0, stream>>>(pts, means3D, scales, boxes, pcell);
    la_cell<<<NCELL, NTHR, 0, stream>>>(pts, means3D, opac, sem, cov3D,
                                        boxes, pcell, out);
}

// Round 7
// 34.418 us; speedup vs baseline: 4.2339x; 1.1139x over previous
//
#include <hip/hip_runtime.h>
#include <math.h>

// Problem constants (from reference)
#define P_TOTAL 10000
#define G_TOTAL 6400
#define C_CLS   18
#define REC_DW  40        // gaussian record stride in dwords (160 B)
#define CS_SH   3         // cell = 8 voxels = 4 m
#define NCX     25
#define NCELL   (NCX * NCX)
#define MAXE    256       // entry slots per cell (mean fill ~51, max ~100)
#define TPP     16        // threads per point in gather
#define NTHR    256
#define PREP_LANES 32     // lanes per gaussian in prep

// Record layout (dwords):
// [4..7]   float: mux, muy, muz, opacity
// [8..11]  float: cxx, cyy, czz, cxy
// [12..13] float: cyz, cxz
// [16..33] float: sem[18]

__global__ void la_zero(int* __restrict__ counts) {
    int i = threadIdx.x + blockIdx.x * blockDim.x;
    if (i < NCELL) counts[i] = 0;
}

// Wide prep: 32 lanes per gaussian. Lanes 0..27 copy one record dword each;
// lanes 28..31 compute the voxel box (broadcast loads) and scatter <=3 cell
// entries each. Max cells = 3x3 (w<=12 -> <=3 cells/axis).
__global__ void __launch_bounds__(NTHR)
la_prep(const float* __restrict__ means3D,
        const float* __restrict__ opacities,
        const float* __restrict__ semantics,
        const float* __restrict__ scales,
        const float* __restrict__ cov3D,
        float* __restrict__ rec,
        int* __restrict__ counts,
        int4* __restrict__ entries) {
    const int tid  = blockIdx.x * NTHR + threadIdx.x;
    const int g    = tid / PREP_LANES;          // 800 blocks * 256 / 32 = 6400 exact
    const int lane = tid & (PREP_LANES - 1);

    if (lane < 28) {
        // static copy map: record dword <- source element
        float v;
        int dst;
        if (lane < 3) {            // mu
            v = means3D[g * 3 + lane];
            dst = 4 + lane;
        } else if (lane == 3) {    // opacity
            v = opacities[g];
            dst = 7;
        } else if (lane < 10) {    // cov: xx yy zz xy yz xz <- flat 0,4,8,1,5,2
            const int cov_src[6] = {0, 4, 8, 1, 5, 2};
            v = cov3D[(size_t)g * 9 + cov_src[lane - 4]];
            dst = 8 + (lane - 4);
        } else {                   // semantics
            v = semantics[(size_t)g * C_CLS + (lane - 10)];
            dst = 16 + (lane - 10);
        }
        rec[(size_t)g * REC_DW + dst] = v;
    } else {
        // box + scatter (4 lanes, broadcast loads of the same gaussian)
        float mx = means3D[g * 3 + 0];
        float my = means3D[g * 3 + 1];
        float mz = means3D[g * 3 + 2];
        float sx = scales[g * 3 + 0];
        float sy = scales[g * 3 + 1];
        float sz = scales[g * 3 + 2];
        // (mu - PC_MIN)/0.5 == (mu - PC_MIN)*2 exactly
        int mix = (int)((mx + 50.0f) * 2.0f);
        int miy = (int)((my + 50.0f) * 2.0f);
        int miz = (int)((mz + 5.0f) * 2.0f);
        // radii = ceil(max(s)*3.0/0.5): *3.0 rounds, *2 exact
        int r = (int)ceilf((fmaxf(fmaxf(sx, sy), sz) * 3.0f) * 2.0f);
        int w = 2 * r;
        int minx = mix - r, miny = miy - r, minz = miz - r;
        int cx0 = max(minx, 0) >> CS_SH;
        int cx1 = min(minx + w, 199) >> CS_SH;
        int cy0 = max(miny, 0) >> CS_SH;
        int cy1 = min(miny + w, 199) >> CS_SH;
        int nx = cx1 - cx0 + 1;
        int ny = cy1 - cy0 + 1;
        int4 e = make_int4(minx, miny, minz, (w << 16) | g);
        // 9 possible cells (3x3), strided over the 4 scatter lanes
        for (int k = lane - 28; k < 9; k += 4) {
            int dx = k % 3, dy = k / 3;
            if (dx < nx && dy < ny) {
                int cell = (cy0 + dy) * NCX + (cx0 + dx);
                int slot = atomicAdd(&counts[cell], 1);
                if (slot < MAXE) entries[(size_t)cell * MAXE + slot] = e;
            }
        }
    }
}

__global__ void la_gather(const float* __restrict__ pts,
                          const float* __restrict__ rec,
                          const int* __restrict__ counts,
                          const int4* __restrict__ entries,
                          float* __restrict__ out) {
    const int grp  = threadIdx.x >> 4;          // 16 point-groups per block
    const int lane = threadIdx.x & 15;
    const int pt = blockIdx.x * 16 + grp;       // 625 blocks * 16 = 10000
    if (pt >= P_TOTAL) return;

    float px = pts[pt * 3 + 0];
    float py = pts[pt * 3 + 1];
    float pz = pts[pt * 3 + 2];
    int pix = (int)((px + 50.0f) * 2.0f);
    int piy = (int)((py + 50.0f) * 2.0f);
    int piz = (int)((pz + 5.0f) * 2.0f);

    int cell = (piy >> CS_SH) * NCX + (pix >> CS_SH);
    int cnt = min(counts[cell], MAXE);
    const int4* eb = entries + (size_t)cell * MAXE;

    float acc[C_CLS];
#pragma unroll
    for (int c = 0; c < C_CLS; ++c) acc[c] = 0.0f;

#pragma unroll 2
    for (int i = lane; i < cnt; i += TPP) {
        int4 b = eb[i];                          // coalesced 16B within cell
        unsigned w = ((unsigned)b.w) >> 16;
        unsigned ux = (unsigned)(pix - b.x);
        unsigned uy = (unsigned)(piy - b.y);
        unsigned uz = (unsigned)(piz - b.z);
        if (ux <= w && uy <= w && uz <= w) {
            int gid = b.w & 0xffff;
            const float* o = rec + (size_t)gid * REC_DW;
            float4 g0 = *(const float4*)(o + 4);   // mu, op
            float4 g1 = *(const float4*)(o + 8);   // cxx cyy czz cxy
            float2 g2 = *(const float2*)(o + 12);  // cyz cxz
            float dx = px - g0.x, dy = py - g0.y, dz = pz - g0.z;
            float pw = -0.5f * (g1.x * dx * dx + g1.y * dy * dy + g1.z * dz * dz)
                       - g1.w * dx * dy - g2.x * dy * dz - g2.y * dx * dz;
            float wgt = __expf(pw) * g0.w;
            float4 s0 = *(const float4*)(o + 16);
            float4 s1 = *(const float4*)(o + 20);
            float4 s2 = *(const float4*)(o + 24);
            float4 s3 = *(const float4*)(o + 28);
            float2 s4 = *(const float2*)(o + 32);
            acc[0]  = fmaf(wgt, s0.x, acc[0]);  acc[1]  = fmaf(wgt, s0.y, acc[1]);
            acc[2]  = fmaf(wgt, s0.z, acc[2]);  acc[3]  = fmaf(wgt, s0.w, acc[3]);
            acc[4]  = fmaf(wgt, s1.x, acc[4]);  acc[5]  = fmaf(wgt, s1.y, acc[5]);
            acc[6]  = fmaf(wgt, s1.z, acc[6]);  acc[7]  = fmaf(wgt, s1.w, acc[7]);
            acc[8]  = fmaf(wgt, s2.x, acc[8]);  acc[9]  = fmaf(wgt, s2.y, acc[9]);
            acc[10] = fmaf(wgt, s2.z, acc[10]); acc[11] = fmaf(wgt, s2.w, acc[11]);
            acc[12] = fmaf(wgt, s3.x, acc[12]); acc[13] = fmaf(wgt, s3.y, acc[13]);
            acc[14] = fmaf(wgt, s3.z, acc[14]); acc[15] = fmaf(wgt, s3.w, acc[15]);
            acc[16] = fmaf(wgt, s4.x, acc[16]); acc[17] = fmaf(wgt, s4.y, acc[17]);
        }
    }

    // reduce across the 16 lanes of this point-group
#pragma unroll
    for (int m = 8; m >= 1; m >>= 1) {
#pragma unroll
        for (int c = 0; c < C_CLS; ++c)
            acc[c] += __shfl_xor(acc[c], m, 64);
    }

    if (lane == 0) {
        float* dst = out + (size_t)pt * C_CLS;
#pragma unroll
        for (int c = 0; c < C_CLS; ++c) dst[c] = acc[c];
    }
}

extern "C" void kernel_launch(void* const* d_in, const int* in_sizes, int n_in,
                              void* d_out, int out_size, void* d_ws, size_t ws_size,
                              hipStream_t stream) {
    const float* pts      = (const float*)d_in[0];
    const float* means3D  = (const float*)d_in[1];
    const float* opac     = (const float*)d_in[2];
    const float* sem      = (const float*)d_in[3];
    const float* scales   = (const float*)d_in[4];
    const float* cov3D    = (const float*)d_in[5];
    float* out = (float*)d_out;

    char* ws = (char*)d_ws;
    float* rec      = (float*)ws;                              // 1,024,000 B
    int*   counts   = (int*)(ws + 1024000);                    // 2,500 B
    int4*  entries  = (int4*)(ws + 1024000 + 4096);            // 2,560,000 B

    la_zero<<<(NCELL + NTHR - 1) / NTHR, NTHR, 0, stream>>>(counts);
    la_prep<<<(G_TOTAL * PREP_LANES) / NTHR, NTHR, 0, stream>>>(means3D, opac, sem,
                                                                scales, cov3D,
                                                                rec, counts, entries);
    la_gather<<<(P_TOTAL + 15) / 16, NTHR, 0, stream>>>(pts, rec, counts, entries, out);
}